// Round 8
// baseline (1306.768 us; speedup 1.0000x reference)
//
#include <hip/hip_runtime.h>
#include <stdint.h>

typedef __bf16 bf16;
typedef __attribute__((ext_vector_type(8))) __bf16 bf16x8;
typedef __attribute__((ext_vector_type(4))) __bf16 bf16x4;
typedef __attribute__((ext_vector_type(4))) float f32x4;

#define LG_D 128

__device__ __forceinline__ void gload_lds16(const void* g, void* l){
  __builtin_amdgcn_global_load_lds(
      (const __attribute__((address_space(1))) void*)g,
      (__attribute__((address_space(3))) void*)l, 16, 0, 0);
}

// ---------------- zero (cnt_in | cnt_out | tck2[gm] | tcsp[gm]) ----------------
__global__ void zero_kernel(int* a, int n){
  int i = blockIdx.x * blockDim.x + threadIdx.x;
  if(i < n) a[i] = 0;
}

// ---------------- K1: B granulation (all 4 matrices) + degree histogram ----------------
// granule g=(k8,col): out[g*8+j] = in[k8*8+j][col]; one BK=32 tile = 512
// contiguous granules = 8KB. Pads (k>=Ksrc) are ZERO -> tail/overrun steps
// multiply zero-B, so the GEMM needs no k-guards (uniform vmcnt counts).
// Blocks >= nbig+56 do the edge histogram (independent work, hides its latency).
__global__ void k1_gran_hist(const float* __restrict__ next_h, const float* __restrict__ W_conv,
                             const float* __restrict__ W_fus,  const float* __restrict__ cat_W,
                             bf16* __restrict__ Bg, bf16* __restrict__ Wcg,
                             bf16* __restrict__ Wfg, bf16* __restrict__ catWg,
                             int K, int nbig,
                             const int* __restrict__ src, const int* __restrict__ dst,
                             int* cnt_out, int* cnt_in, int E){
  int b = blockIdx.x;
  const int ngran = nbig + 56;
  if(b >= ngran){
    int e = (b - ngran) * 256 + threadIdx.x;
    if(e < E){
      atomicAdd(&cnt_out[src[e]], 1);
      atomicAdd(&cnt_in[dst[e]], 1);
    }
    return;
  }
  const float* srcp; bf16* dstp; int g0, Ksrc;
  if(b < nbig)          { srcp = next_h; dstp = Bg;    g0 = b * 256;               Ksrc = K;   }
  else if(b < nbig + 16){ srcp = W_conv; dstp = Wcg;   g0 = (b - nbig) * 256;      Ksrc = 128; }
  else if(b < nbig + 32){ srcp = W_fus;  dstp = Wfg;   g0 = (b - nbig - 16) * 256; Ksrc = 128; }
  else                  { srcp = cat_W;  dstp = catWg; g0 = (b - nbig - 32) * 256; Ksrc = 256; }
  int g = g0 + threadIdx.x;
  int k8 = g >> 7, col = g & 127;
  bf16 tmp[8];
  #pragma unroll
  for(int j = 0; j < 8; j++){
    int k = k8 * 8 + j;
    tmp[j] = (k < Ksrc) ? (bf16)srcp[(size_t)k * LG_D + col] : (bf16)0.f;
  }
  *(bf16x8*)(dstp + (size_t)g * 8) = *(bf16x8*)tmp;
}

// ---------------- BM=32 BK=32 depth-2 copy-free pipelined MFMA GEMM body ----------------
// R1-frozen K-loop. FUSE=1 (only with ASRC=0,EPI=0,SK=1): after writing the
// split-K partial, atomic fan-in on tc[gx]; the LAST of the 2 chunk-blocks
// reads its partner's partial, adds its own in-register acc, and runs the
// R3-verified barrier-free fuse: swizzled-LDS transpose -> A-frags, B-frags
// direct from L2-hot Wf granules -> H[:,128:256] *= rsqrt(deg_out). No polling.

#define GB_LOADA(G, S) \
    do{ if(ASRC == 1) loadAb((G), ab[S]); \
        else loadA1((G), au0[S], au1[S]); }while(0)

#define GB_WAITV() \
    do{ if(ASRC == 1)      asm volatile("s_waitcnt vmcnt(5)" ::: "memory"); \
        else               asm volatile("s_waitcnt vmcnt(6)" ::: "memory"); }while(0)

#define GB_STEP(S) \
  { \
    GB_WAITV(); \
    __builtin_amdgcn_s_barrier(); \
    __builtin_amdgcn_sched_barrier(0); \
    stageB(step0 + t + 2, (S + 2) % 3); \
    GB_LOADA(step0 + t + 2, (S + 2) % 3); \
    bf16x8 af; \
    if(ASRC == 1) af = ab[S]; \
    else af = cvt(au0[S], au1[S]); \
    const bf16* bp = &Bs[S][(lg * 128 + l16) * 8]; \
    _Pragma("unroll") \
    for(int ni = 0; ni < 8; ni++){ \
      bf16x8 bq = *(const bf16x8*)(bp + ni * 128); \
      acc[ni] = __builtin_amdgcn_mfma_f32_16x16x32_bf16(af, bq, acc[ni], 0, 0, 0); \
    } \
    t++; \
    if(t == nt) goto kdone; \
  }

template<int ASRC, int EPI, int FUSE>
__device__ __forceinline__ void gemm_body(bf16 (*Bs)[4096], int gx, int gy,
    const float* __restrict__ Af, const bf16* __restrict__ Abf,
    const bf16* __restrict__ Bg,
    float* __restrict__ Cf, bf16* __restrict__ Cb,
    int M, int K, int spc, int TOT, size_t partStride, int yoff,
    const int* __restrict__ cntdeg,
    const bf16* __restrict__ Wf, int* __restrict__ tc)
{
  const int tid  = threadIdx.x;
  const int lane = tid & 63, w = tid >> 6;
  const int l16  = lane & 15, lg = lane >> 4;
  const int row0 = gx * 32;
  const int step0 = gy * spc;
  int nt = TOT - step0; if(nt > spc) nt = spc;

  f32x4 acc[8] = {};

  int r = row0 + w * 16 + l16; if(r > M - 1) r = M - 1;   // store is guarded
  const float* Apf = Af  ? Af  + (size_t)r * K + lg * 8 : nullptr;
  const bf16*  Apb = Abf ? Abf + (size_t)r * K + lg * 8 : nullptr;

  f32x4 au0[3], au1[3];
  bf16x8 ab[3];

  auto stageB = [&](int g, int buf){
    const bf16* sp = Bg + ((size_t)g * 512 + tid) * 8;
    #pragma unroll
    for(int i = 0; i < 4; i++)
      gload_lds16(sp + i * 1024, &Bs[buf][(i * 128 + w * 64) * 8]);
  };
  auto aoff = [&](int g){
    int kk = g * 32;
    return (kk + lg * 8 < K) ? kk : 0;    // OOB k-slots hit zero-B granules
  };
  auto loadA1 = [&](int g, f32x4& u0, f32x4& u1){
    int off = aoff(g);
    u0 = *(const f32x4*)(Apf + off);
    u1 = *(const f32x4*)(Apf + off + 4);
  };
  auto loadAb = [&](int g, bf16x8& b){
    int off = aoff(g);
    b = *(const bf16x8*)(Apb + off);
  };
  auto cvt = [&](const f32x4& u0, const f32x4& u1){
    bf16x8 a;
    a[0]=(bf16)u0.x; a[1]=(bf16)u0.y; a[2]=(bf16)u0.z; a[3]=(bf16)u0.w;
    a[4]=(bf16)u1.x; a[5]=(bf16)u1.y; a[6]=(bf16)u1.z; a[7]=(bf16)u1.w;
    return a;
  };

  // prologue: issue sets for tiles step0, step0+1 into slots 0,1
  stageB(step0, 0);     GB_LOADA(step0, 0);
  stageB(step0 + 1, 1); GB_LOADA(step0 + 1, 1);

  {
    int t = 0;
    while(true){
      GB_STEP(0)
      GB_STEP(1)
      GB_STEP(2)
    }
  }
kdone:

  // ---- epilogues (C/D layout: col = l16, row = lg*4 + j; m89-verified) ----
  if(EPI == 0){
    float* Co = Cf + (size_t)gy * partStride;
    #pragma unroll
    for(int j = 0; j < 4; j++){
      int rr = row0 + w * 16 + lg * 4 + j;
      if(rr < M){
        #pragma unroll
        for(int ni = 0; ni < 8; ni++)
          Co[(size_t)rr * LG_D + ni * 16 + l16] = acc[ni][j];
      }
    }
  } else {
    #pragma unroll
    for(int j = 0; j < 4; j++){
      int rr = row0 + w * 16 + lg * 4 + j;
      if(rr < M){
        float sc = rsqrtf((float)(cntdeg[rr] + 1));
        #pragma unroll
        for(int ni = 0; ni < 8; ni++)
          Cb[(size_t)rr * 256 + yoff + ni * 16 + l16] = (bf16)(acc[ni][j] * sc);
      }
    }
  }

  if constexpr (FUSE == 1){
    __shared__ int fin;
    __threadfence();                 // release my partial (each thread)
    __syncthreads();                 // drains vmcnt(0): stores + overrun prefetch
    if(tid == 0)
      fin = (__hip_atomic_fetch_add(tc + gx, 1, __ATOMIC_ACQ_REL,
                                    __HIP_MEMORY_SCOPE_AGENT) == 1);
    __syncthreads();
    if(!fin) return;
    __threadfence();                 // acquire partner's partial

    // partner partial + own acc -> bf16, XOR-swizzled into Bs[0] (8KB):
    // byte = (row*256 + col*2) ^ ((row&7)<<4)   [R3-verified]
    const float* Pp = Cf + (size_t)(gy ^ 1) * partStride;
    char* Asp = (char*)&Bs[0][0];
    #pragma unroll
    for(int ni = 0; ni < 8; ni++){
      #pragma unroll
      for(int j = 0; j < 4; j++){
        int row = w * 16 + lg * 4 + j;
        int rr = row0 + row; if(rr > M - 1) rr = M - 1;   // pad rows: garbage ok, discarded
        float s = acc[ni][j] + Pp[(size_t)rr * LG_D + ni * 16 + l16];
        int off = ((row * 256 + (ni * 16 + l16) * 2) ^ ((row & 7) << 4));
        *(bf16*)(Asp + off) = (bf16)s;
      }
    }
    __syncthreads();                 // As visible to both waves

    // fuse GEMM: A-frags from swizzled LDS, B-frags direct from global Wf
    // (L2-hot, no LDS staging -> no overwrite hazard)  [R3-verified]
    f32x4 acc2[8] = {};
    const int rowA = w * 16 + l16;
    #pragma unroll
    for(int t2 = 0; t2 < 4; t2++){
      int aoff2 = ((rowA * 256 + t2 * 64 + lg * 16) ^ ((rowA & 7) << 4));
      bf16x8 af2 = *(const bf16x8*)(Asp + aoff2);
      const bf16* wp = Wf + (size_t)((t2 * 4 + lg) * 128) * 8;
      #pragma unroll
      for(int ni = 0; ni < 8; ni++){
        bf16x8 bq = *(const bf16x8*)(wp + (ni * 16 + l16) * 8);
        acc2[ni] = __builtin_amdgcn_mfma_f32_16x16x32_bf16(af2, bq, acc2[ni], 0, 0, 0);
      }
    }
    #pragma unroll
    for(int j = 0; j < 4; j++){
      int rr = row0 + w * 16 + lg * 4 + j;
      if(rr < M){
        float sc = rsqrtf((float)(cntdeg[rr] + 1));
        #pragma unroll
        for(int ni = 0; ni < 8; ni++)
          Cb[(size_t)rr * 256 + 128 + ni * 16 + l16] = (bf16)(acc2[ni][j] * sc);
      }
    }
  }
}

// ---------------- 128-thread exclusive scan (rides inside the k2 dispatch) ----------------
__device__ void scan_body(const int* __restrict__ cnt, int* __restrict__ q, int n, int* sh){
  const int tid = threadIdx.x;
  const int lane = tid & 63, wid = tid >> 6;
  int carry = 0;
  for(int base = 0; base < n; base += 128){
    int i = base + tid;
    int v = (i < n) ? cnt[i] : 0;
    int x = v;
    #pragma unroll
    for(int off = 1; off < 64; off <<= 1){
      int y = __shfl_up(x, off, 64);
      if(lane >= off) x += y;
    }
    if(lane == 63) sh[wid] = x;
    __syncthreads();
    int w0 = sh[0], w1 = sh[1];
    int excl = x - v + (wid ? w0 : 0) + carry;
    if(i < n) q[i] = excl;
    carry += w0 + w1;
    __syncthreads();
  }
}

// ---------------- K2: inc GEMM (split-K x2, fan-in W_fus fuse) + trailing scan ----------------
// R1-frozen grid: 1250 balanced streamers first (all resident at t=0,
// 6 blocks/CU x 256 CU = 1536 slots), scan as the single trailing block.
// The later of each split-K pair fuses -> H[:,128:256] (overlapped with stream).
__global__ __launch_bounds__(128, 3) void k2_inc_scan(
    const float* __restrict__ Af, const bf16* __restrict__ Bg, float* __restrict__ Cf,
    const bf16* __restrict__ Wfg, bf16* __restrict__ H,
    const int* __restrict__ cnt_out, int* __restrict__ tc,
    int M, int K, int spc, int TOT, size_t partStride, int gm,
    const int* __restrict__ cnt_in, int* __restrict__ q){
  __shared__ bf16 Bs[3][4096];
  int bx = blockIdx.x;
  if(bx >= 2 * gm){
    scan_body(cnt_in, q, M, (int*)&Bs[0][0]);
    return;
  }
  gemm_body<0, 0, 1>(Bs, bx % gm, bx / gm, Af, nullptr, Bg, Cf, H,
                     M, K, spc, TOT, partStride, 0, cnt_out, Wfg, tc);
}

// ---------------- K3: curr_h GEMM + CSR scatter tail ----------------
__global__ __launch_bounds__(128, 3) void k3_h_scatter(
    const float* __restrict__ curr_h, const bf16* __restrict__ Wcg,
    bf16* __restrict__ H, int M, const int* __restrict__ cnt_out, int gm,
    const int* __restrict__ src, const int* __restrict__ dst,
    int* __restrict__ q, int* __restrict__ csr, int E){
  __shared__ bf16 Bs[3][4096];
  int bx = blockIdx.x;
  if(bx >= gm){
    int e = (bx - gm) * 128 + threadIdx.x;
    if(e < E){
      int d = dst[e];
      int pos = atomicAdd(&q[d], 1);   // q[d]: start -> end as edges land
      csr[pos] = src[e];
    }
    return;
  }
  gemm_body<0, 1, 0>(Bs, bx, 0, curr_h, nullptr, Wcg, nullptr, H,
                     M, 128, 4, 4, 0, 0, cnt_out, nullptr, nullptr);
}

// ---------------- K4: fused SpMM (1 wave/row, R1-parallelism) + fan-in cat+LN ----------------
// 5000 blocks x 4 waves = 20000 gather waves (TLP preserved). 8 blocks cover a
// 32-row tile; the 8th arrival (atomic fan-in, no polling) runs the cat GEMM +
// LayerNorm for the tile, A-frags direct from global V (R7-verified phase B).
__global__ __launch_bounds__(256) void spmm_cat_ln(
    const bf16* __restrict__ H, const int* __restrict__ q, const int* __restrict__ csr,
    const float* __restrict__ b_conv, const float* __restrict__ conv_w,
    const float* __restrict__ b_fus,  const float* __restrict__ td_w,
    bf16* __restrict__ V, int M,
    const bf16* __restrict__ catWg, const float* __restrict__ cat_b,
    const float* __restrict__ lng, const float* __restrict__ lnb,
    float* __restrict__ res, int* __restrict__ tc){
  __shared__ float sums[2][2][16][2];      // [rt][ch][row][s1/s2]
  __shared__ int fin;
  const int tid = threadIdx.x;
  const int lane = tid & 63, wd = tid >> 6;
  const int row = blockIdx.x * 4 + wd;

  if(row < M){
    const int end = q[row];
    const int beg = row ? q[row - 1] : 0;
    const int n   = end - beg;

    float acc[4];
    {
      bf16x4 h = *(const bf16x4*)(H + (size_t)row * 256 + lane * 4);   // self-loop
      #pragma unroll
      for(int j = 0; j < 4; j++) acc[j] = (float)h[j];
    }
    bf16x4 f0, f1;
    if(n > 0) f0 = *(const bf16x4*)(H + (size_t)csr[beg] * 256 + lane * 4);
    if(n > 1) f1 = *(const bf16x4*)(H + (size_t)csr[beg + 1] * 256 + lane * 4);
    int i = 0;
    for(; i + 2 < n; i++){
      bf16x4 c = f0; f0 = f1;
      f1 = *(const bf16x4*)(H + (size_t)csr[beg + i + 2] * 256 + lane * 4);
      #pragma unroll
      for(int j = 0; j < 4; j++) acc[j] += (float)c[j];
    }
    if(i < n){
      #pragma unroll
      for(int j = 0; j < 4; j++) acc[j] += (float)f0[j];
      i++;
    }
    if(i < n){
      #pragma unroll
      for(int j = 0; j < 4; j++) acc[j] += (float)f1[j];
    }

    float rs = rsqrtf((float)(n + 1));                // deg_in
    const bool low = lane < 32;
    const int ci = low ? lane * 4 : (lane - 32) * 4;
    const float* bp_ = low ? b_conv : b_fus;
    const float* wp_ = low ? conv_w : td_w;
    float mine[4], other[4];
    #pragma unroll
    for(int j = 0; j < 4; j++)
      mine[j] = (acc[j] * rs + bp_[ci + j]) * wp_[ci + j];
    #pragma unroll
    for(int j = 0; j < 4; j++)
      other[j] = __shfl_xor(mine[j], 32, 64);
    if(low){
      bf16x4 o1, o2;
      #pragma unroll
      for(int j = 0; j < 4; j++){
        float cs = mine[j], td = other[j];
        o1[j] = (bf16)(fmaxf(cs, 0.f) + fmaxf(td, 0.f));
        o2[j] = (bf16)(cs + td);
      }
      *(bf16x4*)(V + (size_t)row * 256 + lane * 4)       = o1;
      *(bf16x4*)(V + (size_t)row * 256 + 128 + lane * 4) = o2;
    }
  }

  // ---- fan-in: 8th arrival for the 32-row tile does cat GEMM + LN ----
  const int tx = blockIdx.x >> 3;            // tile index
  __threadfence();                           // release V writes
  __syncthreads();
  if(tid == 0){
    int rows = M - tx * 32; if(rows > 32) rows = 32;
    int tgt = (rows + 3) >> 2;               // blocks covering this tile
    fin = (__hip_atomic_fetch_add(tc + tx, 1, __ATOMIC_ACQ_REL,
                                  __HIP_MEMORY_SCOPE_AGENT) == tgt - 1);
  }
  __syncthreads();
  if(!fin) return;
  __threadfence();                           // acquire other blocks' V rows

  // phase B (R7-verified): wave wd -> rowtile rt=wd&1, colhalf ch=wd>>1
  const int row0 = tx * 32;
  const int l16 = lane & 15, lg = lane >> 4;
  const int rt = wd & 1, ch = wd >> 1;
  f32x4 acc2[4] = {};
  const int arow0 = row0 + rt * 16 + l16;
  const int ar = arow0 < M ? arow0 : M - 1;  // pad rows: results discarded
  #pragma unroll
  for(int ks = 0; ks < 8; ks++){
    bf16x8 af = *(const bf16x8*)(V + (size_t)ar * 256 + ks * 32 + lg * 8);
    const bf16* wp = catWg + (size_t)((ks * 4 + lg) * 128) * 8;
    #pragma unroll
    for(int ni = 0; ni < 4; ni++){
      bf16x8 bq = *(const bf16x8*)(wp + (ch * 64 + ni * 16 + l16) * 8);
      acc2[ni] = __builtin_amdgcn_mfma_f32_16x16x32_bf16(af, bq, acc2[ni], 0, 0, 0);
    }
  }

  float gg[4], bb[4], bs[4];
  #pragma unroll
  for(int ni = 0; ni < 4; ni++){
    int col = ch * 64 + ni * 16 + l16;
    gg[ni] = lng[col]; bb[ni] = lnb[col]; bs[ni] = cat_b[col];
  }
  float s1[4] = {}, s2[4] = {};
  #pragma unroll
  for(int ni = 0; ni < 4; ni++){
    #pragma unroll
    for(int j = 0; j < 4; j++){
      float v = acc2[ni][j] + bs[ni];
      acc2[ni][j] = v;
      s1[j] += v; s2[j] += v * v;
    }
  }
  #pragma unroll
  for(int j = 0; j < 4; j++){
    #pragma unroll
    for(int off = 1; off < 16; off <<= 1){
      s1[j] += __shfl_xor(s1[j], off, 64);
      s2[j] += __shfl_xor(s2[j], off, 64);
    }
  }
  if(l16 == 0){
    #pragma unroll
    for(int j = 0; j < 4; j++){
      sums[rt][ch][lg * 4 + j][0] = s1[j];
      sums[rt][ch][lg * 4 + j][1] = s2[j];
    }
  }
  __syncthreads();
  #pragma unroll
  for(int j = 0; j < 4; j++){
    float t1 = s1[j] + sums[rt][ch ^ 1][lg * 4 + j][0];
    float t2 = s2[j] + sums[rt][ch ^ 1][lg * 4 + j][1];
    float mu  = t1 * (1.f / 128.f);
    float inv = rsqrtf(t2 * (1.f / 128.f) - mu * mu + 1e-5f);
    int grow = row0 + rt * 16 + lg * 4 + j;
    if(grow < M){
      #pragma unroll
      for(int ni = 0; ni < 4; ni++)
        res[(size_t)grow * LG_D + ch * 64 + ni * 16 + l16] =
            (acc2[ni][j] - mu) * inv * gg[ni] + bb[ni];
    }
  }
}

// ---------------- launch ----------------

extern "C" void kernel_launch(void* const* d_in, const int* in_sizes, int n_in,
                              void* d_out, int out_size, void* d_ws, size_t ws_size,
                              hipStream_t stream){
  const float* curr_h   = (const float*)d_in[0];
  const float* next_h   = (const float*)d_in[1];
  const float* curr_inc = (const float*)d_in[2];
  const int*   src      = (const int*)d_in[3];
  const int*   dst      = (const int*)d_in[4];
  const float* W_conv   = (const float*)d_in[5];
  const float* b_conv   = (const float*)d_in[6];
  const float* W_fus    = (const float*)d_in[7];
  const float* b_fus    = (const float*)d_in[8];
  const float* conv_w   = (const float*)d_in[9];
  const float* td_w     = (const float*)d_in[10];
  const float* cat_W    = (const float*)d_in[11];
  const float* cat_b    = (const float*)d_in[12];
  const float* ln_g     = (const float*)d_in[13];
  const float* ln_b     = (const float*)d_in[14];

  const int D    = LG_D;
  const int M    = in_sizes[0] / D;      // 20000
  const int Kinc = in_sizes[1] / D;      // 10000
  const int E    = in_sizes[3];          // 320000

  const int TOT1    = (Kinc + 31) / 32;  // 313 BK=32 tiles
  const int SPC1    = (TOT1 + 1) / 2;    // 157 tiles/chunk (split-K x2)
  const int K8ALLOC = (TOT1 + 2) * 4;    // 1260 k8-groups (incl. prefetch-overrun pad)
  const int NBIG    = (K8ALLOC * 128) / 256;  // 630 granulate blocks for Bg

  const int gm = (M + 31) / 32;          // 625

  // workspace carve (256B aligned)
  char* p = (char*)d_ws;
  auto alloc = [&](size_t bytes){ char* q = p; p += (bytes + 255) & ~(size_t)255; return q; };
  float* part   = (float*)alloc((size_t)2 * M * D * 4);
  bf16*  H      = (bf16*) alloc((size_t)M * 256 * 2);
  bf16*  V      = (bf16*) alloc((size_t)M * 256 * 2);
  bf16*  Bg     = (bf16*) alloc((size_t)K8ALLOC * 128 * 16);
  bf16*  Wcg    = (bf16*) alloc((size_t)32 * 128 * 16);    // k8 pad to 32 (8 tiles)
  bf16*  Wfg    = (bf16*) alloc((size_t)32 * 128 * 16);
  bf16*  catWg  = (bf16*) alloc((size_t)48 * 128 * 16);    // k8 pad to 48 (12 tiles)
  int*   cnts   = (int*)  alloc((size_t)(2 * M + 2 * gm) * 4); // cnt_in|cnt_out|tck2|tcsp
  int*   q      = (int*)  alloc((size_t)M * 4);            // CSR starts -> ends
  int*   csr    = (int*)  alloc((size_t)E * 4);
  int* cnt_in  = cnts;
  int* cnt_out = cnts + M;
  int* tck2    = cnts + 2 * M;
  int* tcsp    = cnts + 2 * M + gm;
  (void)ws_size; (void)n_in; (void)out_size;

  float* res = (float*)d_out;
  const size_t pstride = (size_t)M * D;

  // 1. zero degree counters + fan-in counters
  zero_kernel<<<(2 * M + 2 * gm + 255) / 256, 256, 0, stream>>>(cnts, 2 * M + 2 * gm);

  // 2. granulate all B matrices + edge histogram (merged, independent work)
  k1_gran_hist<<<NBIG + 56 + (E + 255) / 256, 256, 0, stream>>>(
      next_h, W_conv, W_fus, cat_W, Bg, Wcg, Wfg, catWg, Kinc, NBIG,
      src, dst, cnt_out, cnt_in, E);

  // 3. 800MB inc stream (split-K x2, 1250 balanced streamers all resident at
  //    t=0) + fan-in W_fus fuse -> H[:,128:256] + trailing scan  [R1 grid]
  k2_inc_scan<<<2 * gm + 1, 128, 0, stream>>>(
      curr_inc, Bg, part, Wfg, H, cnt_out, tck2,
      M, Kinc, SPC1, TOT1, pstride, gm, cnt_in, q);

  // 4. curr_h GEMM -> H[:,0:128] + CSR scatter tail
  k3_h_scatter<<<gm + (E + 127) / 128, 128, 0, stream>>>(
      curr_h, Wcg, H, M, cnt_out, gm, src, dst, q, csr, E);

  // 5. SpMM (R1 parallelism: 1 wave/row) + fan-in cat GEMM + LayerNorm -> res
  spmm_cat_ln<<<(M + 3) / 4, 256, 0, stream>>>(H, q, csr,
      b_conv, conv_w, b_fus, td_w, V, M,
      catWg, cat_b, ln_g, ln_b, res, tcsp);
}